// Round 3
// baseline (120.677 us; speedup 1.0000x reference)
//
#include <hip/hip_runtime.h>

// RaySamples: per-ray (K=128) exclusive scan of delta*density, then
//   T = exp(-acc_excl), w = T[k] - T[k+1]  (== alpha*T algebraically).
// Layout trick: K=128 fp32 = 2 rays per wave64 at one float4 per lane;
// rays are contiguous, so flat float4 index == coalesced access AND the
// ray boundary lands exactly on the lane-32 boundary -> segmented scan
// via __shfl_up(width=32).
//
// This revision: two chunks per thread (i, i+stride) with all four input
// loads issued before any dependent compute (2x memory-level parallelism;
// the two shuffle-scan chains interleave), and nontemporal load/store on
// all streams (zero reuse -> don't allocate in L2). Memory-bound:
// 134 MB total traffic, ~21 us streaming floor.
//
// NOTE: __builtin_nontemporal_* requires a NATIVE vector type — HIP's
// float4 is a class and is rejected. Use ext_vector_type(4) (same
// size/alignment, lowers to global_{load,store}_dwordx4 ... nt).

typedef float f4 __attribute__((ext_vector_type(4)));

__global__ __launch_bounds__(256) void RaySamples_34454227648765_kernel(
    const float* __restrict__ dens, const float* __restrict__ delt,
    float* __restrict__ outw, float* __restrict__ outT, int n4)
{
    const int stride = gridDim.x * blockDim.x;           // in float4 units
    const int i0 = blockIdx.x * blockDim.x + threadIdx.x;
    const int i1 = i0 + stride;
    const int lane = threadIdx.x & 31;

    const f4* __restrict__ d4 = reinterpret_cast<const f4*>(dens);
    const f4* __restrict__ l4 = reinterpret_cast<const f4*>(delt);
    f4* __restrict__ w4 = reinterpret_cast<f4*>(outw);
    f4* __restrict__ t4 = reinterpret_cast<f4*>(outT);

    // n4 and stride are both multiples of 32, so the (i1 < n4) branch is
    // uniform across each 32-lane scan segment.
    if (i1 < n4) {
        const f4 dA = __builtin_nontemporal_load(d4 + i0);
        const f4 lA = __builtin_nontemporal_load(l4 + i0);
        const f4 dB = __builtin_nontemporal_load(d4 + i1);
        const f4 lB = __builtin_nontemporal_load(l4 + i1);

        float A0 = dA.x * lA.x, A1 = dA.y * lA.y,
              A2 = dA.z * lA.z, A3 = dA.w * lA.w;
        float B0 = dB.x * lB.x, B1 = dB.y * lB.y,
              B2 = dB.z * lB.z, B3 = dB.w * lB.w;

        float sA = A0 + A1 + A2 + A3;   // lane totals
        float sB = B0 + B1 + B2 + B3;

        // Two independent inclusive scans across the 32-lane ray segments;
        // chains interleave for ILP over the ds_bpermute latency.
        float incA = sA, incB = sB;
        #pragma unroll
        for (int off = 1; off < 32; off <<= 1) {
            float vA = __shfl_up(incA, off, 32);
            float vB = __shfl_up(incB, off, 32);
            incA += (lane >= off) ? vA : 0.0f;
            incB += (lane >= off) ? vB : 0.0f;
        }

        float aA0 = incA - sA;          // exclusive optical depth
        float aA1 = aA0 + A0, aA2 = aA1 + A1, aA3 = aA2 + A2, aA4 = aA3 + A3;
        float aB0 = incB - sB;
        float aB1 = aB0 + B0, aB2 = aB1 + B1, aB3 = aB2 + B2, aB4 = aB3 + B3;

        float tA0 = __expf(-aA0), tA1 = __expf(-aA1), tA2 = __expf(-aA2),
              tA3 = __expf(-aA3), tA4 = __expf(-aA4);
        float tB0 = __expf(-aB0), tB1 = __expf(-aB1), tB2 = __expf(-aB2),
              tB3 = __expf(-aB3), tB4 = __expf(-aB4);

        f4 WA; WA.x = tA0 - tA1; WA.y = tA1 - tA2; WA.z = tA2 - tA3; WA.w = tA3 - tA4;
        f4 TA; TA.x = tA0; TA.y = tA1; TA.z = tA2; TA.w = tA3;
        f4 WB; WB.x = tB0 - tB1; WB.y = tB1 - tB2; WB.z = tB2 - tB3; WB.w = tB3 - tB4;
        f4 TB; TB.x = tB0; TB.y = tB1; TB.z = tB2; TB.w = tB3;

        __builtin_nontemporal_store(WA, w4 + i0);
        __builtin_nontemporal_store(TA, t4 + i0);
        __builtin_nontemporal_store(WB, w4 + i1);
        __builtin_nontemporal_store(TB, t4 + i1);
    } else if (i0 < n4) {
        // Generic tail (never taken for N*K divisible by 8*blockDim; kept
        // for shape robustness). Segment-uniform because n4 % 32 == 0.
        const f4 d  = __builtin_nontemporal_load(d4 + i0);
        const f4 dl = __builtin_nontemporal_load(l4 + i0);

        float dd0 = d.x * dl.x, dd1 = d.y * dl.y,
              dd2 = d.z * dl.z, dd3 = d.w * dl.w;
        float s = dd0 + dd1 + dd2 + dd3;
        float inc = s;
        #pragma unroll
        for (int off = 1; off < 32; off <<= 1) {
            float v = __shfl_up(inc, off, 32);
            inc += (lane >= off) ? v : 0.0f;
        }
        float a0 = inc - s;
        float a1 = a0 + dd0, a2 = a1 + dd1, a3 = a2 + dd2, a4 = a3 + dd3;
        float t0 = __expf(-a0), t1 = __expf(-a1), t2 = __expf(-a2),
              t3 = __expf(-a3), t4v = __expf(-a4);
        f4 W; W.x = t0 - t1; W.y = t1 - t2; W.z = t2 - t3; W.w = t3 - t4v;
        f4 T; T.x = t0; T.y = t1; T.z = t2; T.w = t3;
        __builtin_nontemporal_store(W, w4 + i0);
        __builtin_nontemporal_store(T, t4 + i0);
    }
}

extern "C" void kernel_launch(void* const* d_in, const int* in_sizes, int n_in,
                              void* d_out, int out_size, void* d_ws, size_t ws_size,
                              hipStream_t stream) {
    const float* dens = (const float*)d_in[0];   // densities [N,K,1] fp32
    const float* delt = (const float*)d_in[1];   // deltas    [N,K,1] fp32
    float* out = (float*)d_out;                  // [weights | transmittance]

    const int NK = in_sizes[0];                  // N*K = 8388608
    const int n4 = NK / 4;                       // float4 quads
    float* outw = out;
    float* outT = out + NK;

    const int block = 256;
    const int threads_needed = (n4 + 1) / 2;     // 2 chunks per thread
    const int grid = (threads_needed + block - 1) / block;   // 4096 blocks
    RaySamples_34454227648765_kernel<<<grid, block, 0, stream>>>(
        dens, delt, outw, outT, n4);
}

// Round 4
// 109.982 us; speedup vs baseline: 1.0972x; 1.0972x over previous
//
#include <hip/hip_runtime.h>

// RaySamples: per-ray (K=128) exclusive scan of delta*density, then
//   T = exp(-acc_excl), w = T[k] - T[k+1]  (== alpha*T algebraically).
// Layout trick: K=128 fp32 = 2 rays per wave64 at one float4 per lane;
// rays are contiguous, so flat float4 index == coalesced access AND the
// ray boundary lands exactly on the lane-32 boundary -> segmented scan
// via __shfl_up(width=32).
//
// R3 post-mortem: NT hints on LOADS regressed ~8 us — inputs (64 MiB)
// are L3-resident across timed iterations (fill re-poison is write-only
// streaming), and nt loads bypass that. So: PLAIN loads (let L3 serve
// them), NT stores only (outputs are re-poisoned each iteration; zero
// caching value, and keeping them out of L3 preserves input residency).
// Keep 2-chunk-per-thread for load MLP ahead of the serialized scan.

typedef float f4 __attribute__((ext_vector_type(4)));

__global__ __launch_bounds__(256) void RaySamples_34454227648765_kernel(
    const float* __restrict__ dens, const float* __restrict__ delt,
    float* __restrict__ outw, float* __restrict__ outT, int n4)
{
    const int stride = gridDim.x * blockDim.x;           // in float4 units
    const int i0 = blockIdx.x * blockDim.x + threadIdx.x;
    const int i1 = i0 + stride;
    const int lane = threadIdx.x & 31;

    const f4* __restrict__ d4 = reinterpret_cast<const f4*>(dens);
    const f4* __restrict__ l4 = reinterpret_cast<const f4*>(delt);
    f4* __restrict__ w4 = reinterpret_cast<f4*>(outw);
    f4* __restrict__ t4 = reinterpret_cast<f4*>(outT);

    // n4 and stride are both multiples of 32, so the (i1 < n4) branch is
    // uniform across each 32-lane scan segment.
    if (i1 < n4) {
        // Plain (cacheable) loads — L3 serves these across iterations.
        const f4 dA = d4[i0];
        const f4 lA = l4[i0];
        const f4 dB = d4[i1];
        const f4 lB = l4[i1];

        float A0 = dA.x * lA.x, A1 = dA.y * lA.y,
              A2 = dA.z * lA.z, A3 = dA.w * lA.w;
        float B0 = dB.x * lB.x, B1 = dB.y * lB.y,
              B2 = dB.z * lB.z, B3 = dB.w * lB.w;

        float sA = A0 + A1 + A2 + A3;   // lane totals
        float sB = B0 + B1 + B2 + B3;

        // Two independent inclusive scans across the 32-lane ray segments;
        // chains interleave for ILP over the ds_bpermute latency.
        float incA = sA, incB = sB;
        #pragma unroll
        for (int off = 1; off < 32; off <<= 1) {
            float vA = __shfl_up(incA, off, 32);
            float vB = __shfl_up(incB, off, 32);
            incA += (lane >= off) ? vA : 0.0f;
            incB += (lane >= off) ? vB : 0.0f;
        }

        float aA0 = incA - sA;          // exclusive optical depth
        float aA1 = aA0 + A0, aA2 = aA1 + A1, aA3 = aA2 + A2, aA4 = aA3 + A3;
        float aB0 = incB - sB;
        float aB1 = aB0 + B0, aB2 = aB1 + B1, aB3 = aB2 + B2, aB4 = aB3 + B3;

        float tA0 = __expf(-aA0), tA1 = __expf(-aA1), tA2 = __expf(-aA2),
              tA3 = __expf(-aA3), tA4 = __expf(-aA4);
        float tB0 = __expf(-aB0), tB1 = __expf(-aB1), tB2 = __expf(-aB2),
              tB3 = __expf(-aB3), tB4 = __expf(-aB4);

        f4 WA; WA.x = tA0 - tA1; WA.y = tA1 - tA2; WA.z = tA2 - tA3; WA.w = tA3 - tA4;
        f4 TA; TA.x = tA0; TA.y = tA1; TA.z = tA2; TA.w = tA3;
        f4 WB; WB.x = tB0 - tB1; WB.y = tB1 - tB2; WB.z = tB2 - tB3; WB.w = tB3 - tB4;
        f4 TB; TB.x = tB0; TB.y = tB1; TB.z = tB2; TB.w = tB3;

        __builtin_nontemporal_store(WA, w4 + i0);
        __builtin_nontemporal_store(TA, t4 + i0);
        __builtin_nontemporal_store(WB, w4 + i1);
        __builtin_nontemporal_store(TB, t4 + i1);
    } else if (i0 < n4) {
        // Generic tail (never taken for N*K divisible by 8*blockDim; kept
        // for shape robustness). Segment-uniform because n4 % 32 == 0.
        const f4 d  = d4[i0];
        const f4 dl = l4[i0];

        float dd0 = d.x * dl.x, dd1 = d.y * dl.y,
              dd2 = d.z * dl.z, dd3 = d.w * dl.w;
        float s = dd0 + dd1 + dd2 + dd3;
        float inc = s;
        #pragma unroll
        for (int off = 1; off < 32; off <<= 1) {
            float v = __shfl_up(inc, off, 32);
            inc += (lane >= off) ? v : 0.0f;
        }
        float a0 = inc - s;
        float a1 = a0 + dd0, a2 = a1 + dd1, a3 = a2 + dd2, a4 = a3 + dd3;
        float t0 = __expf(-a0), t1 = __expf(-a1), t2 = __expf(-a2),
              t3 = __expf(-a3), t4v = __expf(-a4);
        f4 W; W.x = t0 - t1; W.y = t1 - t2; W.z = t2 - t3; W.w = t3 - t4v;
        f4 T; T.x = t0; T.y = t1; T.z = t2; T.w = t3;
        __builtin_nontemporal_store(W, w4 + i0);
        __builtin_nontemporal_store(T, t4 + i0);
    }
}

extern "C" void kernel_launch(void* const* d_in, const int* in_sizes, int n_in,
                              void* d_out, int out_size, void* d_ws, size_t ws_size,
                              hipStream_t stream) {
    const float* dens = (const float*)d_in[0];   // densities [N,K,1] fp32
    const float* delt = (const float*)d_in[1];   // deltas    [N,K,1] fp32
    float* out = (float*)d_out;                  // [weights | transmittance]

    const int NK = in_sizes[0];                  // N*K = 8388608
    const int n4 = NK / 4;                       // float4 quads
    float* outw = out;
    float* outT = out + NK;

    const int block = 256;
    const int threads_needed = (n4 + 1) / 2;     // 2 chunks per thread
    const int grid = (threads_needed + block - 1) / block;   // 4096 blocks
    RaySamples_34454227648765_kernel<<<grid, block, 0, stream>>>(
        dens, delt, outw, outT, n4);
}